// Round 6
// baseline (518.790 us; speedup 1.0000x reference)
//
#include <hip/hip_runtime.h>
#include <hip/hip_bf16.h>
#include <stdint.h>

#define N_NODES 20000
#define N_EDGES 640000
#define DIM 128
#define TPB 10           // tiles (of 128 edges) per block
#define EDGE_GRID 500    // 500 * 10 * 128 = 640000

using bf16x8 = __attribute__((ext_vector_type(8))) short;
using f32x4  = __attribute__((ext_vector_type(4))) float;

static __device__ __forceinline__ unsigned short f2bf(float f) {
    union { float f; unsigned int u; } v; v.f = f;
    unsigned int r = v.u + 0x7FFFu + ((v.u >> 16) & 1u);
    return (unsigned short)(r >> 16);
}

static __device__ __forceinline__ void glds16(const unsigned short* g, char* lds) {
    __builtin_amdgcn_global_load_lds(
        (const __attribute__((address_space(1))) unsigned int*)(const void*)g,
        (__attribute__((address_space(3))) unsigned int*)(void*)lds, 16, 0, 0);
}

// LDS write->read fence, wave-local: pin compiler order + wait ds_writes landed.
// (HW LDS is in-order per wave; the fence exists to stop compiler reordering,
// which broke the barrier-free R5 variant. lgkm-only: global loads stay in flight.)
static __device__ __forceinline__ void lds_fence() {
    __builtin_amdgcn_sched_barrier(0);
    asm volatile("s_waitcnt lgkmcnt(0)" ::: "memory");
    __builtin_amdgcn_sched_barrier(0);
}
// WAR pin: only DS ops may not cross (VMEM/VALU/MFMA free to move).
static __device__ __forceinline__ void ds_order() {
    __builtin_amdgcn_sched_barrier(0x7F);
}

// ---------------- prep: bf16 node table, transposed bf16 weights, zero counts ----------------
__global__ void prep_kernel(const float* __restrict__ node_feat,
                            const float* __restrict__ W1e, const float* __restrict__ W2e,
                            const float* __restrict__ W1n, const float* __restrict__ W2n,
                            unsigned short* __restrict__ node_bf,
                            unsigned short* __restrict__ Wt1e, unsigned short* __restrict__ Wt2e,
                            unsigned short* __restrict__ Wt1n, unsigned short* __restrict__ Wt2n,
                            int* __restrict__ counts) {
    int tid = blockIdx.x * blockDim.x + threadIdx.x;
    int stride = gridDim.x * blockDim.x;
    for (int i = tid; i < N_NODES * DIM / 8; i += stride) {
        const float* p = node_feat + (size_t)i * 8;
        float4 f0 = *(const float4*)p;
        float4 f1 = *(const float4*)(p + 4);
        bf16x8 a;
        a[0] = (short)f2bf(f0.x); a[1] = (short)f2bf(f0.y);
        a[2] = (short)f2bf(f0.z); a[3] = (short)f2bf(f0.w);
        a[4] = (short)f2bf(f1.x); a[5] = (short)f2bf(f1.y);
        a[6] = (short)f2bf(f1.z); a[7] = (short)f2bf(f1.w);
        *(bf16x8*)(node_bf + (size_t)i * 8) = a;
    }
    // Wt[n][k] = W[k][n]
    for (int i = tid; i < DIM * 384; i += stride) { int n = i / 384, k = i % 384; Wt1e[i] = f2bf(W1e[k * DIM + n]); }
    for (int i = tid; i < DIM * DIM; i += stride) { int n = i / DIM, k = i % DIM; Wt2e[i] = f2bf(W2e[k * DIM + n]); }
    for (int i = tid; i < DIM * 256; i += stride) { int n = i / 256, k = i % 256; Wt1n[i] = f2bf(W1n[k * DIM + n]); }
    for (int i = tid; i < DIM * DIM; i += stride) { int n = i / DIM, k = i % DIM; Wt2n[i] = f2bf(W2n[k * DIM + n]); }
    for (int i = tid; i < N_NODES; i += stride) counts[i] = 0;
}

// ---------------- CSR build ----------------
__global__ void count_kernel(const int* __restrict__ eidx, int* __restrict__ counts) {
    int e = blockIdx.x * blockDim.x + threadIdx.x;
    if (e < N_EDGES) atomicAdd(&counts[eidx[N_EDGES + e]], 1);
}

__global__ void scan_kernel(const int* __restrict__ counts, int* __restrict__ offsets,
                            int* __restrict__ cursor) {
    __shared__ int wsum[16];
    const int CH = 20;
    int tid = threadIdx.x;
    int lane = tid & 63, wid = tid >> 6;
    int base = tid * CH;
    int s = 0;
    #pragma unroll
    for (int j = 0; j < CH; ++j) { int i = base + j; s += (i < N_NODES) ? counts[i] : 0; }
    int chunk = s;
    #pragma unroll
    for (int off = 1; off < 64; off <<= 1) { int t = __shfl_up(s, off, 64); if (lane >= off) s += t; }
    if (lane == 63) wsum[wid] = s;
    __syncthreads();
    if (tid == 0) {
        int run = 0;
        for (int w = 0; w < 16; ++w) { int t = wsum[w]; wsum[w] = run; run += t; }
    }
    __syncthreads();
    int run = wsum[wid] + s - chunk;
    for (int j = 0; j < CH; ++j) {
        int i = base + j;
        if (i < N_NODES) { offsets[i] = run; cursor[i] = run; run += counts[i]; }
    }
}

__global__ void scatter_kernel(const int* __restrict__ eidx, int* __restrict__ cursor,
                               int* __restrict__ elist) {
    int e = blockIdx.x * blockDim.x + threadIdx.x;
    if (e < N_EDGES) {
        int p = atomicAdd(&cursor[eidx[N_EDGES + e]], 1);
        elist[p] = e;
    }
}

// ---------------- edge MLP: persistent block, weights resident in LDS ----------------
// 500 blocks x 256 threads (4 waves), 1 block/CU (144 KB LDS). Stage Wt1e (96 KB)
// + Wt2e (32 KB) ONCE (16B-slot XOR swizzle via pre-swizzled global source), then
// 10 tiles of 128 edges with no workgroup barriers in the tile loop. Wave-private
// LDS staging (h chunks + f32 epilogue strips) is fenced with sched_barrier +
// lgkmcnt(0) -- lgkm-only, so global prefetches stay in flight across tiles.
__launch_bounds__(256, 1)
__global__ void edge_kernel(const float* __restrict__ edge_feat,
                            const int* __restrict__ eidx,
                            const unsigned short* __restrict__ node_bf,
                            const unsigned short* __restrict__ Wt1e,
                            const unsigned short* __restrict__ Wt2e,
                            const float* __restrict__ b1e,
                            const float* __restrict__ b2e,
                            float* __restrict__ out_edge) {
    __shared__ char ldsW1[98304];        // [n=128][48 slots of 16B], low-3 slot bits ^ (n&7)
    __shared__ char ldsW2[32768];        // [n=128][16 slots], low-3 slot bits ^ (n&7)
    __shared__ char ldsS[4][4096];       // per-wave: h chunk (2 KB) / f32 strip (4 KB)
    const int tid = threadIdx.x;
    const int wv = tid >> 6;
    const int l = tid & 63;
    const int lr = l & 15;
    const int kg = l >> 4;
    char* S = ldsS[wv];
    const int eBase = blockIdx.x * (TPB * 128);

    // ---- stage all weights once (linear LDS dest, pre-swizzled global source) ----
    #pragma unroll
    for (int c = 0; c < 24; ++c) {
        int Sc = c * 256 + tid;          // 16B chunk index, 0..6143
        int n = Sc / 48, sp = Sc % 48;
        int s = (sp & 56) | ((sp ^ n) & 7);
        glds16(Wt1e + n * 384 + s * 8, ldsW1 + Sc * 16);
    }
    #pragma unroll
    for (int c = 0; c < 8; ++c) {
        int Sc = c * 256 + tid;          // 0..2047
        int n = Sc >> 4, sp = Sc & 15;
        int s = (sp & 8) | ((sp ^ n) & 7);
        glds16(Wt2e + n * 128 + s * 8, ldsW2 + Sc * 16);
    }

    float b1r[8], b2r[8];
    #pragma unroll
    for (int tt = 0; tt < 8; ++tt) { b1r[tt] = b1e[tt * 16 + lr]; b2r[tt] = b2e[tt * 16 + lr]; }

    // ---- register gather buffers (double-buffered across tiles) ----
    float4 E0[4][2][2], E1[4][2][2];
    bf16x8 N0[8][2], N1[8][2];

    auto prefRaw = [&](int t, float4 (&E)[4][2][2], bf16x8 (&NB)[8][2]) {
        int tb = eBase + t * 128 + wv * 32;
        int e0 = tb + lr, e1 = tb + 16 + lr;
        int s0 = eidx[e0], d0 = eidx[N_EDGES + e0];
        int s1 = eidx[e1], d1 = eidx[N_EDGES + e1];
        #pragma unroll
        for (int st = 0; st < 4; ++st) {
            const float* p0 = edge_feat + (long)e0 * DIM + st * 32 + kg * 8;
            const float* p1 = edge_feat + (long)e1 * DIM + st * 32 + kg * 8;
            E[st][0][0] = *(const float4*)p0; E[st][0][1] = *(const float4*)(p0 + 4);
            E[st][1][0] = *(const float4*)p1; E[st][1][1] = *(const float4*)(p1 + 4);
        }
        #pragma unroll
        for (int st = 0; st < 4; ++st) {
            NB[st][0]     = *(const bf16x8*)(node_bf + (long)s0 * DIM + st * 32 + kg * 8);
            NB[st][1]     = *(const bf16x8*)(node_bf + (long)s1 * DIM + st * 32 + kg * 8);
            NB[st + 4][0] = *(const bf16x8*)(node_bf + (long)d0 * DIM + st * 32 + kg * 8);
            NB[st + 4][1] = *(const bf16x8*)(node_bf + (long)d1 * DIM + st * 32 + kg * 8);
        }
    };

    f32x4 acc[2][8];

    // GEMM1: converts edge fp32->bf16 inline (keeps register pressure down)
    auto gemm1 = [&](float4 (&E)[4][2][2], bf16x8 (&NB)[8][2]) {
        bf16x8 EB[4][2];
        #pragma unroll
        for (int st = 0; st < 4; ++st)
            #pragma unroll
            for (int rt = 0; rt < 2; ++rt) {
                bf16x8 a;
                a[0] = (short)f2bf(E[st][rt][0].x); a[1] = (short)f2bf(E[st][rt][0].y);
                a[2] = (short)f2bf(E[st][rt][0].z); a[3] = (short)f2bf(E[st][rt][0].w);
                a[4] = (short)f2bf(E[st][rt][1].x); a[5] = (short)f2bf(E[st][rt][1].y);
                a[6] = (short)f2bf(E[st][rt][1].z); a[7] = (short)f2bf(E[st][rt][1].w);
                EB[st][rt] = a;
            }
        #pragma unroll
        for (int rt = 0; rt < 2; ++rt)
            #pragma unroll
            for (int tt = 0; tt < 8; ++tt) acc[rt][tt] = (f32x4){0.f, 0.f, 0.f, 0.f};
        #pragma unroll
        for (int s = 0; s < 12; ++s) {
            int sl = s * 4 + kg;
            int sp = (sl & 56) | ((sl ^ lr) & 7);
            #pragma unroll
            for (int tt = 0; tt < 8; ++tt) {
                bf16x8 B = *(const bf16x8*)(ldsW1 + (tt * 16 + lr) * 768 + sp * 16);
                #pragma unroll
                for (int rt = 0; rt < 2; ++rt) {
                    bf16x8 A = (s < 4) ? EB[s][rt] : NB[s - 4][rt];
                    acc[rt][tt] = __builtin_amdgcn_mfma_f32_16x16x32_bf16(A, B, acc[rt][tt], 0, 0, 0);
                }
            }
        }
    };

    // GEMM2 + epilogue for tile t (consumes acc)
    auto tail = [&](int t) {
        int tb = eBase + t * 128 + wv * 32;
        f32x4 acc2[2][8];
        #pragma unroll
        for (int rt = 0; rt < 2; ++rt)
            #pragma unroll
            for (int tt = 0; tt < 8; ++tt) acc2[rt][tt] = (f32x4){0.f, 0.f, 0.f, 0.f};

        // ---- GEMM2, chunked through the 2 KB wave-private h buffer, fenced ----
        #pragma unroll
        for (int q = 0; q < 4; ++q) {
            // write chunk q: h cols [q*32, q*32+32), rows 0..31, 16B-slot XOR swizzle
            #pragma unroll
            for (int rt = 0; rt < 2; ++rt)
                #pragma unroll
                for (int t2 = 0; t2 < 2; ++t2) {
                    int tt = q * 2 + t2;
                    #pragma unroll
                    for (int r = 0; r < 4; ++r) {
                        int row = rt * 16 + kg * 4 + r;
                        float x = acc[rt][tt][r] + b1r[tt];
                        float h = x / (1.0f + __expf(-x));
                        int slot = t2 * 2 + (lr >> 3);
                        int byte = row * 64 + ((slot ^ ((row >> 1) & 3)) << 4) + (lr & 7) * 2;
                        *(unsigned short*)(S + byte) = f2bf(h);
                    }
                }
            lds_fence();                   // writes visible before cross-lane reads
            bf16x8 A2[2];
            #pragma unroll
            for (int rt = 0; rt < 2; ++rt) {
                int row = rt * 16 + lr;
                int byte = row * 64 + ((kg ^ ((row >> 1) & 3)) << 4);
                A2[rt] = *(const bf16x8*)(S + byte);
            }
            ds_order();                    // next chunk's writes stay after these reads
            int sl2 = q * 4 + kg;
            int sp2 = (sl2 & 8) | ((sl2 ^ lr) & 7);
            #pragma unroll
            for (int tt = 0; tt < 8; ++tt) {
                bf16x8 B = *(const bf16x8*)(ldsW2 + (tt * 16 + lr) * 256 + sp2 * 16);
                #pragma unroll
                for (int rt = 0; rt < 2; ++rt)
                    acc2[rt][tt] = __builtin_amdgcn_mfma_f32_16x16x32_bf16(A2[rt], B, acc2[rt][tt], 0, 0, 0);
            }
        }

        // ---- epilogue: 4 fenced f32 strips [16 rows][64 cols], then coalesced
        //      float4 residual-add + store ----
        #pragma unroll
        for (int rt = 0; rt < 2; ++rt)
            #pragma unroll
            for (int ch = 0; ch < 2; ++ch) {
                #pragma unroll
                for (int t2 = 0; t2 < 4; ++t2) {
                    int tt = ch * 4 + t2;
                    #pragma unroll
                    for (int r = 0; r < 4; ++r) {
                        int row = kg * 4 + r;
                        int col = t2 * 16 + lr;
                        int byte = row * 256 + (((col >> 2) ^ (row & 15)) << 4) + (col & 3) * 4;
                        *(float*)(S + byte) = acc2[rt][tt][r] + b2r[tt];
                    }
                }
                lds_fence();
                #pragma unroll
                for (int i = 0; i < 4; ++i) {
                    int row = (l >> 4) + i * 4;
                    int slot = l & 15;
                    int byte = row * 256 + ((slot ^ (row & 15)) << 4);
                    float4 v = *(const float4*)(S + byte);
                    long gidx = (long)(tb + rt * 16 + row) * DIM + ch * 64 + slot * 4;
                    float4 rs = *(const float4*)(edge_feat + gidx);
                    v.x += rs.x; v.y += rs.y; v.z += rs.z; v.w += rs.w;
                    *(float4*)(out_edge + gidx) = v;
                }
                ds_order();                // next strip's writes stay after these reads
            }
    };

    // ---- prologue ----
    prefRaw(0, E0, N0);
    __syncthreads();          // weights staged (drains vmcnt incl. tile-0 gathers)

    // ---- main loop: 2 tiles per iteration, no workgroup barriers ----
    #pragma unroll 1
    for (int it = 0; it < TPB / 2; ++it) {
        int t0 = it * 2;
        prefRaw(t0 + 1, E1, N1);
        gemm1(E0, N0);
        tail(t0);
        if (t0 + 2 < TPB) prefRaw(t0 + 2, E0, N0);
        gemm1(E1, N1);
        tail(t0 + 1);
    }
}

// ---------------- mean aggregation (CSR pull, unrolled x4 gathers) ----------------
__global__ void agg_kernel(const float* __restrict__ edge_out,
                           const int* __restrict__ offsets, const int* __restrict__ counts,
                           const int* __restrict__ elist,
                           unsigned short* __restrict__ agg_bf) {
    int n = blockIdx.x * 4 + (threadIdx.x >> 6);
    int l = threadIdx.x & 63;
    if (n >= N_NODES) return;
    int off = offsets[n], cnt = counts[n];
    float a0 = 0.f, a1 = 0.f;
    int i = 0;
    for (; i + 4 <= cnt; i += 4) {
        int e0 = elist[off + i], e1 = elist[off + i + 1];
        int e2 = elist[off + i + 2], e3 = elist[off + i + 3];
        float2 v0 = *(const float2*)(edge_out + (long)e0 * DIM + l * 2);
        float2 v1 = *(const float2*)(edge_out + (long)e1 * DIM + l * 2);
        float2 v2 = *(const float2*)(edge_out + (long)e2 * DIM + l * 2);
        float2 v3 = *(const float2*)(edge_out + (long)e3 * DIM + l * 2);
        a0 += v0.x + v1.x + v2.x + v3.x;
        a1 += v0.y + v1.y + v2.y + v3.y;
    }
    for (; i < cnt; ++i) {
        int e = elist[off + i];
        float2 v = *(const float2*)(edge_out + (long)e * DIM + l * 2);
        a0 += v.x; a1 += v.y;
    }
    float inv = 1.0f / fmaxf((float)cnt, 1.0f);
    agg_bf[n * DIM + l * 2] = f2bf(a0 * inv);
    agg_bf[n * DIM + l * 2 + 1] = f2bf(a1 * inv);
}

// ---------------- node MLP ----------------
#define SLICE_B 8448
__launch_bounds__(256, 4)
__global__ void node_kernel(const float* __restrict__ node_feat,
                            const unsigned short* __restrict__ node_bf,
                            const unsigned short* __restrict__ agg_bf,
                            const unsigned short* __restrict__ Wt1n,
                            const unsigned short* __restrict__ Wt2n,
                            const float* __restrict__ b1n,
                            const float* __restrict__ b2n,
                            float* __restrict__ out_node) {
    __shared__ char lds[4][SLICE_B];
    const int tid = threadIdx.x;
    const int wv = tid >> 6;
    const int l = tid & 63;
    const int lr = l & 15;
    const int kg = l >> 4;
    char* slice = lds[wv];

    const int nBase = blockIdx.x * 128;
    const int wBase = nBase + wv * 32;

    int rowc[2];
    #pragma unroll
    for (int rt = 0; rt < 2; ++rt) {
        int row = wBase + rt * 16 + lr;
        rowc[rt] = row < N_NODES ? row : N_NODES - 1;
    }

    f32x4 acc[2][8];
    #pragma unroll
    for (int rt = 0; rt < 2; ++rt)
        #pragma unroll
        for (int t = 0; t < 8; ++t) acc[rt][t] = (f32x4){0.f, 0.f, 0.f, 0.f};

    #pragma unroll
    for (int s = 0; s < 8; ++s) {
        const int kk = s * 32 + kg * 8;
        bf16x8 A[2];
        if (s < 4) {
            #pragma unroll
            for (int rt = 0; rt < 2; ++rt)
                A[rt] = *(const bf16x8*)(node_bf + (long)rowc[rt] * DIM + kk);
        } else {
            #pragma unroll
            for (int rt = 0; rt < 2; ++rt)
                A[rt] = *(const bf16x8*)(agg_bf + (long)rowc[rt] * DIM + (kk - 128));
        }
        #pragma unroll
        for (int t = 0; t < 8; ++t) {
            bf16x8 B = *(const bf16x8*)(Wt1n + (t * 16 + lr) * 256 + kk);
            #pragma unroll
            for (int rt = 0; rt < 2; ++rt)
                acc[rt][t] = __builtin_amdgcn_mfma_f32_16x16x32_bf16(A[rt], B, acc[rt][t], 0, 0, 0);
        }
    }

    #pragma unroll
    for (int rt = 0; rt < 2; ++rt) {
        #pragma unroll
        for (int t = 0; t < 8; ++t) {
            float b1 = b1n[t * 16 + lr];
            int col = t * 16 + lr;
            #pragma unroll
            for (int r = 0; r < 4; ++r) {
                int row = rt * 16 + kg * 4 + r;
                float x = acc[rt][t][r] + b1;
                float h = x / (1.0f + __expf(-x));
                int byte = (row * 256 + col * 2) ^ ((row & 7) << 4);
                *(unsigned short*)(slice + byte) = f2bf(h);
            }
        }
    }
    __syncthreads();

    f32x4 acc2[2][8];
    #pragma unroll
    for (int rt = 0; rt < 2; ++rt)
        #pragma unroll
        for (int t = 0; t < 8; ++t) acc2[rt][t] = (f32x4){0.f, 0.f, 0.f, 0.f};

    #pragma unroll
    for (int s = 0; s < 4; ++s) {
        const int kk = s * 32 + kg * 8;
        bf16x8 A[2];
        #pragma unroll
        for (int rt = 0; rt < 2; ++rt) {
            int row = rt * 16 + lr;
            int byte = (row * 256 + kk * 2) ^ ((row & 7) << 4);
            A[rt] = *(const bf16x8*)(slice + byte);
        }
        #pragma unroll
        for (int t = 0; t < 8; ++t) {
            bf16x8 B = *(const bf16x8*)(Wt2n + (t * 16 + lr) * DIM + kk);
            #pragma unroll
            for (int rt = 0; rt < 2; ++rt)
                acc2[rt][t] = __builtin_amdgcn_mfma_f32_16x16x32_bf16(A[rt], B, acc2[rt][t], 0, 0, 0);
        }
    }
    __syncthreads();

    #pragma unroll
    for (int rt = 0; rt < 2; ++rt) {
        float* sf = (float*)slice;
        #pragma unroll
        for (int t = 0; t < 8; ++t) {
            float b2 = b2n[t * 16 + lr];
            int col = t * 16 + lr;
            #pragma unroll
            for (int r = 0; r < 4; ++r) {
                int row = kg * 4 + r;
                int colp = col ^ (row & 12);
                sf[row * 132 + colp] = acc2[rt][t][r] + b2;
            }
        }
        __syncthreads();
        #pragma unroll
        for (int rr = 0; rr < 8; ++rr) {
            int row = rr * 2 + (l >> 5);
            int c4 = (l & 31) * 4;
            int cswz = c4 ^ (row & 12);
            float4 v = *(const float4*)(sf + row * 132 + cswz);
            int grow = wBase + rt * 16 + row;
            if (grow < N_NODES) {
                long gidx = (long)grow * DIM + c4;
                float4 rsd = *(const float4*)(node_feat + gidx);
                v.x += rsd.x; v.y += rsd.y; v.z += rsd.z; v.w += rsd.w;
                *(float4*)(out_node + gidx) = v;
            }
        }
        __syncthreads();
    }
}

extern "C" void kernel_launch(void* const* d_in, const int* in_sizes, int n_in,
                              void* d_out, int out_size, void* d_ws, size_t ws_size,
                              hipStream_t stream) {
    const float* node_feat = (const float*)d_in[0];
    const float* edge_feat = (const float*)d_in[1];
    const int*   eidx      = (const int*)d_in[2];
    const float* W1e = (const float*)d_in[3];
    const float* b1e = (const float*)d_in[4];
    const float* W2e = (const float*)d_in[5];
    const float* b2e = (const float*)d_in[6];
    const float* W1n = (const float*)d_in[7];
    const float* b1n = (const float*)d_in[8];
    const float* W2n = (const float*)d_in[9];
    const float* b2n = (const float*)d_in[10];

    char* ws = (char*)d_ws;
    size_t off = 0;
    auto alloc = [&](size_t bytes) {
        void* p = ws + off;
        off += (bytes + 255) & ~(size_t)255;
        return p;
    };
    unsigned short* node_bf = (unsigned short*)alloc((size_t)N_NODES * DIM * 2);
    unsigned short* agg_bf  = (unsigned short*)alloc((size_t)N_NODES * DIM * 2);
    unsigned short* Wt1e    = (unsigned short*)alloc((size_t)DIM * 384 * 2);
    unsigned short* Wt2e    = (unsigned short*)alloc((size_t)DIM * DIM * 2);
    unsigned short* Wt1n    = (unsigned short*)alloc((size_t)DIM * 256 * 2);
    unsigned short* Wt2n    = (unsigned short*)alloc((size_t)DIM * DIM * 2);
    int* counts  = (int*)alloc((size_t)N_NODES * 4);
    int* offsets = (int*)alloc((size_t)N_NODES * 4);
    int* cursor  = (int*)alloc((size_t)N_NODES * 4);
    int* elist   = (int*)alloc((size_t)N_EDGES * 4);

    float* out_node = (float*)d_out;
    float* out_edge = out_node + (size_t)N_NODES * DIM;

    prep_kernel<<<512, 256, 0, stream>>>(node_feat, W1e, W2e, W1n, W2n,
                                         node_bf, Wt1e, Wt2e, Wt1n, Wt2n, counts);
    count_kernel<<<(N_EDGES + 255) / 256, 256, 0, stream>>>(eidx, counts);
    scan_kernel<<<1, 1024, 0, stream>>>(counts, offsets, cursor);
    scatter_kernel<<<(N_EDGES + 255) / 256, 256, 0, stream>>>(eidx, cursor, elist);
    edge_kernel<<<EDGE_GRID, 256, 0, stream>>>(edge_feat, eidx, node_bf, Wt1e, Wt2e,
                                               b1e, b2e, out_edge);
    agg_kernel<<<(N_NODES + 3) / 4, 256, 0, stream>>>(out_edge, offsets, counts, elist, agg_bf);
    node_kernel<<<(N_NODES + 127) / 128, 256, 0, stream>>>(node_feat, node_bf, agg_bf,
                                                           Wt1n, Wt2n, b1n, b2n, out_node);
}